// Round 7
// baseline (4196.515 us; speedup 1.0000x reference)
//
#include <hip/hip_runtime.h>
#include <math.h>

namespace {
constexpr int kB = 2, kN = 6, kC = 64, kD = 41, kH = 32, kW = 88;
constexpr int kHW = kH * kW;                  // 2816
constexpr int kBN = kB * kN;                  // 12
constexpr int kCols = kBN * kHW;              // 33792 softmax columns
constexpr int kNX = 200;
constexpr int kPts = kBN * kD * kHW;          // 1,385,472 points
constexpr int kVox = kNX * kNX;               // 40000
}  // namespace

// Blocks fp-contraction across each step (hipcc default -ffp-contract=fast
// fused my previous "per-op" attempts into fma — R1==R3, R5==R6 bit-equal).
#define FP_BARRIER(x) asm volatile("" : "+v"(x))

// Kernel 1: per-(b,n,h,w) softmax stats over D: column max and sum(exp).
__global__ void __launch_bounds__(256) lss_softmax_stats(
    const float* __restrict__ logits, float* __restrict__ cmax,
    float* __restrict__ csum) {
  int col = blockIdx.x * 256 + threadIdx.x;
  if (col >= kCols) return;
  int bn = col / kHW;
  int hw = col - bn * kHW;
  const float* p = logits + (size_t)bn * kD * kHW + hw;
  float m = -INFINITY;
#pragma unroll
  for (int d = 0; d < kD; ++d) m = fmaxf(m, p[(size_t)d * kHW]);
  float s = 0.0f;
#pragma unroll
  for (int d = 0; d < kD; ++d) s += expf(p[(size_t)d * kHW] - m);
  cmax[col] = m;
  csum[col] = s;
}

// Kernel 2: one thread per point; loop over C channels.
// Voxel scheme: TRUE per-op f32 (numpy semantics, no contraction):
//   px = rn(g*100); wx = rn(px-50); tx = rn(wx+50); qx = rn(tx/0.5);
//   ix = floor(qx).  Every step barriered so hipcc cannot fuse mul+add
//   into fma or cancel the +-50 round-trip.
__global__ void __launch_bounds__(256) lss_scatter(
    const float* __restrict__ feat, const float* __restrict__ logits,
    const float* __restrict__ geom, const float* __restrict__ cmax,
    const float* __restrict__ csum, float* __restrict__ out) {
  int i = blockIdx.x * 256 + threadIdx.x;
  if (i >= kPts) return;
  // i = (bn*D + d)*HW + hw  (hw fastest -> coalesced geom/logits loads)
  int hw = i % kHW;
  int bn = i / (kD * kHW);
  int b = (bn >= kN) ? 1 : 0;

  int col = bn * kHW + hw;
  float wgt = expf(logits[i] - cmax[col]) / csum[col];

  size_t g = (size_t)i * 3;
  float gx = geom[g + 0];
  float gy = geom[g + 1];
  float gz = geom[g + 2];

  // world = g*EXTENT + LO, per-op f32
  float px = __fmul_rn(gx, 100.0f); FP_BARRIER(px);
  float py = __fmul_rn(gy, 100.0f); FP_BARRIER(py);
  float pz = __fmul_rn(gz, 20.0f);  FP_BARRIER(pz);
  float wx = __fsub_rn(px, 50.0f);  FP_BARRIER(wx);
  float wy = __fsub_rn(py, 50.0f);  FP_BARRIER(wy);
  float wz = __fsub_rn(pz, 10.0f);  FP_BARRIER(wz);
  // vox = floor((world - LO)/DX), per-op f32
  float tx = __fadd_rn(wx, 50.0f);  FP_BARRIER(tx);
  float ty = __fadd_rn(wy, 50.0f);  FP_BARRIER(ty);
  float tz = __fadd_rn(wz, 10.0f);  FP_BARRIER(tz);
  float qx = __fdiv_rn(tx, 0.5f);   FP_BARRIER(qx);
  float qy = __fdiv_rn(ty, 0.5f);   FP_BARRIER(qy);
  float qz = __fdiv_rn(tz, 20.0f);  FP_BARRIER(qz);
  int ix = (int)floorf(qx);
  int iy = (int)floorf(qy);
  int iz = (int)floorf(qz);
  if ((unsigned)ix >= (unsigned)kNX || (unsigned)iy >= (unsigned)kNX ||
      (unsigned)iz >= 1u)
    return;

  const float* fp = feat + (size_t)bn * kC * kHW + hw;
  float* op = out + (size_t)b * kC * kVox + (size_t)ix * kNX + iy;
#pragma unroll 8
  for (int c = 0; c < kC; ++c) {
    unsafeAtomicAdd(op + (size_t)c * kVox, wgt * fp[(size_t)c * kHW]);
  }
}

extern "C" void kernel_launch(void* const* d_in, const int* in_sizes, int n_in,
                              void* d_out, int out_size, void* d_ws,
                              size_t ws_size, hipStream_t stream) {
  const float* feat = (const float*)d_in[0];
  const float* logits = (const float*)d_in[1];
  const float* geom = (const float*)d_in[2];
  float* out = (float*)d_out;

  float* cmax = (float*)d_ws;  // kCols floats
  float* csum = cmax + kCols;  // kCols floats (total ~270KB)

  // Output is accumulated into -> must start at zero every call.
  hipMemsetAsync(d_out, 0, (size_t)out_size * sizeof(float), stream);

  lss_softmax_stats<<<(kCols + 255) / 256, 256, 0, stream>>>(logits, cmax,
                                                             csum);

  lss_scatter<<<(kPts + 255) / 256, 256, 0, stream>>>(feat, logits, geom,
                                                      cmax, csum, out);
}

// Round 8
// 438.285 us; speedup vs baseline: 9.5748x; 9.5748x over previous
//
#include <hip/hip_runtime.h>
#include <math.h>
#include <stdint.h>

namespace {
constexpr int kB = 2, kN = 6, kC = 64, kD = 41, kH = 32, kW = 88;
constexpr int kHW = kH * kW;                  // 2816
constexpr int kBN = kB * kN;                  // 12
constexpr int kCols = kBN * kHW;              // 33792 softmax columns
constexpr int kNX = 200;
constexpr int kPts = kBN * kD * kHW;          // 1,385,472 points
constexpr int kVox = kNX * kNX;               // 40000
constexpr int kBVox = kB * kVox;              // 80000
constexpr int kPtsPerB = kN * kD * kHW;       // 692736
constexpr int kScanT = 1024;
constexpr int kChunk = (kBVox + kScanT - 1) / kScanT;  // 79
}  // namespace

// Blocks fp-contraction (hipcc -ffp-contract=fast would fuse mul+sub into
// fma and change voxel binning vs the per-op f32 numpy reference).
#define FP_BARRIER(x) asm volatile("" : "+v"(x))

// Kernel 1: per-(b,n,h,w) softmax stats over D: column max and sum(exp).
__global__ void __launch_bounds__(256) lss_softmax_stats(
    const float* __restrict__ logits, float* __restrict__ cmax,
    float* __restrict__ csum) {
  int col = blockIdx.x * 256 + threadIdx.x;
  if (col >= kCols) return;
  int bn = col / kHW;
  int hw = col - bn * kHW;
  const float* p = logits + (size_t)bn * kD * kHW + hw;
  float m = -INFINITY;
#pragma unroll
  for (int d = 0; d < kD; ++d) m = fmaxf(m, p[(size_t)d * kHW]);
  float s = 0.0f;
#pragma unroll
  for (int d = 0; d < kD; ++d) s += expf(p[(size_t)d * kHW] - m);
  cmax[col] = m;
  csum[col] = s;
}

// Kernel 2: transpose feat [bn][c][hw] -> featT [bn][hw][c] (LDS tile),
// so the gather phase reads 256B contiguous per (bn,hw).
__global__ void __launch_bounds__(256) lss_transpose(
    const float* __restrict__ feat, float* __restrict__ featT) {
  __shared__ float t[64][65];
  int bn = blockIdx.x / 44;            // kHW = 44*64
  int hw0 = (blockIdx.x % 44) * 64;
  const float* src = feat + (size_t)bn * kC * kHW;
#pragma unroll
  for (int p = 0; p < 16; ++p) {       // read coalesced in hw
    int c = p * 4 + (threadIdx.x >> 6);
    int hw = threadIdx.x & 63;
    t[hw][c] = src[(size_t)c * kHW + hw0 + hw];
  }
  __syncthreads();
  float* dst = featT + ((size_t)bn * kHW + hw0) * kC;
#pragma unroll
  for (int p = 0; p < 16; ++p) {       // write coalesced in c
    int hw = p * 4 + (threadIdx.x >> 6);
    int c = threadIdx.x & 63;
    dst[(size_t)hw * kC + c] = t[hw][c];
  }
}

// Kernel 3: per point: voxel bin (per-op f32, barriered — matches the
// passing R7 semantics exactly), cache vox id, count per (b,voxel).
__global__ void __launch_bounds__(256) lss_count(
    const float* __restrict__ geom, uint16_t* __restrict__ vox16,
    unsigned* __restrict__ cnt) {
  int i = blockIdx.x * 256 + threadIdx.x;
  if (i >= kPts) return;
  size_t g = (size_t)i * 3;
  float gx = geom[g + 0];
  float gy = geom[g + 1];
  float gz = geom[g + 2];
  float px = __fmul_rn(gx, 100.0f); FP_BARRIER(px);
  float py = __fmul_rn(gy, 100.0f); FP_BARRIER(py);
  float pz = __fmul_rn(gz, 20.0f);  FP_BARRIER(pz);
  float wx = __fsub_rn(px, 50.0f);  FP_BARRIER(wx);
  float wy = __fsub_rn(py, 50.0f);  FP_BARRIER(wy);
  float wz = __fsub_rn(pz, 10.0f);  FP_BARRIER(wz);
  float tx = __fadd_rn(wx, 50.0f);  FP_BARRIER(tx);
  float ty = __fadd_rn(wy, 50.0f);  FP_BARRIER(ty);
  float tz = __fadd_rn(wz, 10.0f);  FP_BARRIER(tz);
  float qx = __fdiv_rn(tx, 0.5f);   FP_BARRIER(qx);
  float qy = __fdiv_rn(ty, 0.5f);   FP_BARRIER(qy);
  float qz = __fdiv_rn(tz, 20.0f);  FP_BARRIER(qz);
  int ix = (int)floorf(qx);
  int iy = (int)floorf(qy);
  int iz = (int)floorf(qz);
  uint16_t v = 0xFFFFu;
  if ((unsigned)ix < (unsigned)kNX && (unsigned)iy < (unsigned)kNX &&
      (unsigned)iz < 1u) {
    int vox = ix * kNX + iy;            // < 40000, fits uint16
    v = (uint16_t)vox;
    int b = i / kPtsPerB;
    atomicAdd(&cnt[b * kVox + vox], 1u);
  }
  vox16[i] = v;
}

// Kernel 4: single-block exclusive scan of cnt[kBVox] in place.
__global__ void __launch_bounds__(kScanT) lss_scan(unsigned* __restrict__ off) {
  __shared__ unsigned lds[kScanT];
  int t = threadIdx.x;
  int lo = t * kChunk, hi = min(lo + kChunk, kBVox);
  unsigned s = 0;
  for (int v = lo; v < hi; ++v) s += off[v];
  lds[t] = s;
  __syncthreads();
  for (int o = 1; o < kScanT; o <<= 1) {
    unsigned x = (t >= o) ? lds[t - o] : 0u;
    __syncthreads();
    lds[t] += x;
    __syncthreads();
  }
  unsigned base = (t > 0) ? lds[t - 1] : 0u;
  for (int v = lo; v < hi; ++v) {
    unsigned c = off[v];
    off[v] = base;
    base += c;
  }
}

// Kernel 5: fill CSR entries {col, wgt}. pos = atomicAdd(off) — after this
// kernel off[v] holds the INCLUSIVE end of segment v (cursor trick).
__global__ void __launch_bounds__(256) lss_fill(
    const float* __restrict__ logits, const uint16_t* __restrict__ vox16,
    const float* __restrict__ cmax, const float* __restrict__ csum,
    unsigned* __restrict__ off, uint2* __restrict__ list) {
  int i = blockIdx.x * 256 + threadIdx.x;
  if (i >= kPts) return;
  unsigned v = vox16[i];
  if (v == 0xFFFFu) return;
  int hw = i % kHW;
  int bn = i / (kD * kHW);
  int b = i / kPtsPerB;
  int col = bn * kHW + hw;
  float wgt = expf(logits[i] - cmax[col]) / csum[col];
  unsigned pos = atomicAdd(&off[b * kVox + (int)v], 1u);
  list[pos] = make_uint2((unsigned)col, __float_as_uint(wgt));
}

// Kernel 6: gather. One wave per (b,voxel); lane = channel. Entry loads are
// wave-uniform (scalarize); featT loads are 256B coalesced; ONE plain store
// per output element, every output cell written (no memset needed).
__global__ void __launch_bounds__(256) lss_gather(
    const unsigned* __restrict__ off, const uint2* __restrict__ list,
    const float* __restrict__ featT, float* __restrict__ out) {
  int wid = threadIdx.x >> 6, lane = threadIdx.x & 63;
  int v = blockIdx.x * 4 + wid;
  if (v >= kBVox) return;
  unsigned s = (v > 0) ? off[v - 1] : 0u;  // post-fill: inclusive ends
  unsigned e = off[v];
  float acc = 0.0f;
  for (; s < e; ++s) {
    uint2 ent = list[s];
    acc += __uint_as_float(ent.y) * featT[(size_t)ent.x * kC + lane];
  }
  int b = v / kVox, vox = v - (v / kVox) * kVox;
  out[(size_t)(b * kC + lane) * kVox + vox] = acc;
}

extern "C" void kernel_launch(void* const* d_in, const int* in_sizes, int n_in,
                              void* d_out, int out_size, void* d_ws,
                              size_t ws_size, hipStream_t stream) {
  const float* feat = (const float*)d_in[0];
  const float* logits = (const float*)d_in[1];
  const float* geom = (const float*)d_in[2];
  float* out = (float*)d_out;

  // Workspace layout (8B-aligned first): total ~23.1 MB
  char* w = (char*)d_ws;
  uint2* list = (uint2*)w;                 w += (size_t)kPts * 8;      // 11.08MB
  float* featT = (float*)w;                w += (size_t)kBN * kHW * kC * 4;  // 8.65MB
  float* cmax = (float*)w;                 w += (size_t)kCols * 4;
  float* csum = (float*)w;                 w += (size_t)kCols * 4;
  unsigned* off = (unsigned*)w;            w += (size_t)kBVox * 4;
  uint16_t* vox16 = (uint16_t*)w;          // 2.77MB

  hipMemsetAsync(off, 0, (size_t)kBVox * sizeof(unsigned), stream);

  lss_softmax_stats<<<(kCols + 255) / 256, 256, 0, stream>>>(logits, cmax,
                                                             csum);
  lss_transpose<<<kBN * (kHW / 64), 256, 0, stream>>>(feat, featT);
  lss_count<<<(kPts + 255) / 256, 256, 0, stream>>>(geom, vox16, off);
  lss_scan<<<1, kScanT, 0, stream>>>(off);
  lss_fill<<<(kPts + 255) / 256, 256, 0, stream>>>(logits, vox16, cmax, csum,
                                                   off, list);
  lss_gather<<<(kBVox + 3) / 4, 256, 0, stream>>>(off, list, featT, out);
}

// Round 9
// 372.667 us; speedup vs baseline: 11.2608x; 1.1761x over previous
//
#include <hip/hip_runtime.h>
#include <math.h>
#include <stdint.h>

namespace {
constexpr int kB = 2, kN = 6, kC = 64, kD = 41, kH = 32, kW = 88;
constexpr int kHW = kH * kW;                  // 2816
constexpr int kBN = kB * kN;                  // 12
constexpr int kCols = kBN * kHW;              // 33792 softmax columns
constexpr int kNX = 200;
constexpr int kPts = kBN * kD * kHW;          // 1,385,472 points
constexpr int kVox = kNX * kNX;               // 40000
constexpr int kBVox = kB * kVox;              // 80000
constexpr int kPtsPerB = kN * kD * kHW;       // 692736
constexpr int kScanT = 1024;
constexpr int kChunk = (kBVox + kScanT - 1) / kScanT;  // 79

constexpr int kCountBlks = (kPts + 255) / 256;          // 5412
constexpr int kTransBlks = kBN * (kHW / 64);            // 528
constexpr int kStatsBlks = (kCols + 255) / 256;         // 132
constexpr int kPrepBlks = kCountBlks + kTransBlks + kStatsBlks;
}  // namespace

// Blocks fp-contraction (hipcc -ffp-contract=fast would fuse mul+sub into
// fma and change voxel binning vs the per-op f32 numpy reference).
#define FP_BARRIER(x) asm volatile("" : "+v"(x))

// Fused prep kernel, block-range partitioned (all three parts independent):
//   blocks [0, kCountBlks)        : voxel-bin + count per (b,voxel)
//   blocks [kCountBlks, +kTrans)  : feat [bn][c][hw] -> featT [bn][hw][c]
//   blocks [.., +kStatsBlks)      : softmax stats (col max, sum of exp)
__global__ void __launch_bounds__(256) lss_prep(
    const float* __restrict__ feat, float* __restrict__ featT,
    const float* __restrict__ logits, float* __restrict__ cmax,
    float* __restrict__ csum, const float* __restrict__ geom,
    uint16_t* __restrict__ vox16, unsigned* __restrict__ cnt) {
  __shared__ float t[64][65];
  int blk = blockIdx.x;
  if (blk < kCountBlks) {
    // ---- count: per-op f32 voxel binning (proven R7 semantics) ----
    int i = blk * 256 + threadIdx.x;
    if (i >= kPts) return;
    size_t g = (size_t)i * 3;
    float gx = geom[g + 0];
    float gy = geom[g + 1];
    float gz = geom[g + 2];
    float px = __fmul_rn(gx, 100.0f); FP_BARRIER(px);
    float py = __fmul_rn(gy, 100.0f); FP_BARRIER(py);
    float pz = __fmul_rn(gz, 20.0f);  FP_BARRIER(pz);
    float wx = __fsub_rn(px, 50.0f);  FP_BARRIER(wx);
    float wy = __fsub_rn(py, 50.0f);  FP_BARRIER(wy);
    float wz = __fsub_rn(pz, 10.0f);  FP_BARRIER(wz);
    float tx = __fadd_rn(wx, 50.0f);  FP_BARRIER(tx);
    float ty = __fadd_rn(wy, 50.0f);  FP_BARRIER(ty);
    float tz = __fadd_rn(wz, 10.0f);  FP_BARRIER(tz);
    float qx = __fdiv_rn(tx, 0.5f);   FP_BARRIER(qx);
    float qy = __fdiv_rn(ty, 0.5f);   FP_BARRIER(qy);
    float qz = __fdiv_rn(tz, 20.0f);  FP_BARRIER(qz);
    int ix = (int)floorf(qx);
    int iy = (int)floorf(qy);
    int iz = (int)floorf(qz);
    uint16_t v = 0xFFFFu;
    if ((unsigned)ix < (unsigned)kNX && (unsigned)iy < (unsigned)kNX &&
        (unsigned)iz < 1u) {
      int vox = ix * kNX + iy;          // < 40000, fits uint16
      v = (uint16_t)vox;
      int b = i / kPtsPerB;
      atomicAdd(&cnt[b * kVox + vox], 1u);
    }
    vox16[i] = v;
  } else if (blk < kCountBlks + kTransBlks) {
    // ---- transpose (LDS tile) ----
    int tb = blk - kCountBlks;
    int bn = tb / 44;                  // kHW = 44*64
    int hw0 = (tb % 44) * 64;
    const float* src = feat + (size_t)bn * kC * kHW;
#pragma unroll
    for (int p = 0; p < 16; ++p) {     // read coalesced in hw
      int c = p * 4 + (threadIdx.x >> 6);
      int hw = threadIdx.x & 63;
      t[hw][c] = src[(size_t)c * kHW + hw0 + hw];
    }
    __syncthreads();
    float* dst = featT + ((size_t)bn * kHW + hw0) * kC;
#pragma unroll
    for (int p = 0; p < 16; ++p) {     // write coalesced in c
      int hw = p * 4 + (threadIdx.x >> 6);
      int c = threadIdx.x & 63;
      dst[(size_t)hw * kC + c] = t[hw][c];
    }
  } else {
    // ---- softmax stats ----
    int col = (blk - kCountBlks - kTransBlks) * 256 + threadIdx.x;
    if (col >= kCols) return;
    int bn = col / kHW;
    int hw = col - bn * kHW;
    const float* p = logits + (size_t)bn * kD * kHW + hw;
    float m = -INFINITY;
#pragma unroll
    for (int d = 0; d < kD; ++d) m = fmaxf(m, p[(size_t)d * kHW]);
    float s = 0.0f;
#pragma unroll
    for (int d = 0; d < kD; ++d) s += expf(p[(size_t)d * kHW] - m);
    cmax[col] = m;
    csum[col] = s;
  }
}

// Single-block exclusive scan of cnt[kBVox] in place.
__global__ void __launch_bounds__(kScanT) lss_scan(unsigned* __restrict__ off) {
  __shared__ unsigned lds[kScanT];
  int t = threadIdx.x;
  int lo = t * kChunk, hi = min(lo + kChunk, kBVox);
  unsigned s = 0;
  for (int v = lo; v < hi; ++v) s += off[v];
  lds[t] = s;
  __syncthreads();
  for (int o = 1; o < kScanT; o <<= 1) {
    unsigned x = (t >= o) ? lds[t - o] : 0u;
    __syncthreads();
    lds[t] += x;
    __syncthreads();
  }
  unsigned base = (t > 0) ? lds[t - 1] : 0u;
  for (int v = lo; v < hi; ++v) {
    unsigned c = off[v];
    off[v] = base;
    base += c;
  }
}

// Fill CSR entries {col, wgt}. pos = atomicAdd(off) — after this kernel
// off[v] holds the INCLUSIVE end of segment v (cursor trick).
__global__ void __launch_bounds__(256) lss_fill(
    const float* __restrict__ logits, const uint16_t* __restrict__ vox16,
    const float* __restrict__ cmax, const float* __restrict__ csum,
    unsigned* __restrict__ off, uint2* __restrict__ list) {
  int i = blockIdx.x * 256 + threadIdx.x;
  if (i >= kPts) return;
  unsigned v = vox16[i];
  if (v == 0xFFFFu) return;
  int hw = i % kHW;
  int bn = i / (kD * kHW);
  int b = i / kPtsPerB;
  int col = bn * kHW + hw;
  float wgt = expf(logits[i] - cmax[col]) / csum[col];
  unsigned pos = atomicAdd(&off[b * kVox + (int)v], 1u);
  list[pos] = make_uint2((unsigned)col, __float_as_uint(wgt));
}

// Gather: one wave per (b,voxel); lane = channel. 4-way unrolled entry loop
// -> 4 independent outstanding featT loads (latency-bound fix). One plain
// store per output element; every cell written (no output memset needed).
__global__ void __launch_bounds__(256) lss_gather(
    const unsigned* __restrict__ off, const uint2* __restrict__ list,
    const float* __restrict__ featT, float* __restrict__ out) {
  int wid = threadIdx.x >> 6, lane = threadIdx.x & 63;
  int v = blockIdx.x * 4 + wid;
  if (v >= kBVox) return;
  unsigned s = (v > 0) ? off[v - 1] : 0u;  // post-fill: inclusive ends
  unsigned e = off[v];
  float acc = 0.0f;
  for (; s + 4 <= e; s += 4) {
    uint2 e0 = list[s + 0];
    uint2 e1 = list[s + 1];
    uint2 e2 = list[s + 2];
    uint2 e3 = list[s + 3];
    float f0 = featT[(size_t)e0.x * kC + lane];
    float f1 = featT[(size_t)e1.x * kC + lane];
    float f2 = featT[(size_t)e2.x * kC + lane];
    float f3 = featT[(size_t)e3.x * kC + lane];
    acc += __uint_as_float(e0.y) * f0;
    acc += __uint_as_float(e1.y) * f1;
    acc += __uint_as_float(e2.y) * f2;
    acc += __uint_as_float(e3.y) * f3;
  }
  for (; s < e; ++s) {
    uint2 ent = list[s];
    acc += __uint_as_float(ent.y) * featT[(size_t)ent.x * kC + lane];
  }
  int b = v / kVox, vox = v - (v / kVox) * kVox;
  out[(size_t)(b * kC + lane) * kVox + vox] = acc;
}

extern "C" void kernel_launch(void* const* d_in, const int* in_sizes, int n_in,
                              void* d_out, int out_size, void* d_ws,
                              size_t ws_size, hipStream_t stream) {
  const float* feat = (const float*)d_in[0];
  const float* logits = (const float*)d_in[1];
  const float* geom = (const float*)d_in[2];
  float* out = (float*)d_out;

  // Workspace layout (8B-aligned first): total ~23.1 MB (proven fit in R8)
  char* w = (char*)d_ws;
  uint2* list = (uint2*)w;                 w += (size_t)kPts * 8;      // 11.08MB
  float* featT = (float*)w;                w += (size_t)kBN * kHW * kC * 4;  // 8.65MB
  float* cmax = (float*)w;                 w += (size_t)kCols * 4;
  float* csum = (float*)w;                 w += (size_t)kCols * 4;
  unsigned* off = (unsigned*)w;            w += (size_t)kBVox * 4;
  uint16_t* vox16 = (uint16_t*)w;          // 2.77MB

  hipMemsetAsync(off, 0, (size_t)kBVox * sizeof(unsigned), stream);

  lss_prep<<<kPrepBlks, 256, 0, stream>>>(feat, featT, logits, cmax, csum,
                                          geom, vox16, off);
  lss_scan<<<1, kScanT, 0, stream>>>(off);
  lss_fill<<<(kPts + 255) / 256, 256, 0, stream>>>(logits, vox16, cmax, csum,
                                                   off, list);
  lss_gather<<<(kBVox + 3) / 4, 256, 0, stream>>>(off, list, featT, out);
}

// Round 10
// 251.124 us; speedup vs baseline: 16.7109x; 1.4840x over previous
//
#include <hip/hip_runtime.h>
#include <math.h>
#include <stdint.h>

namespace {
constexpr int kB = 2, kN = 6, kC = 64, kD = 41, kH = 32, kW = 88;
constexpr int kHW = kH * kW;                  // 2816
constexpr int kBN = kB * kN;                  // 12
constexpr int kCols = kBN * kHW;              // 33792 softmax columns
constexpr int kNX = 200;
constexpr int kPts = kBN * kD * kHW;          // 1,385,472 points
constexpr int kVox = kNX * kNX;               // 40000
constexpr int kBVox = kB * kVox;              // 80000
constexpr int kPtsPerB = kN * kD * kHW;       // 692736

constexpr int kCountBlks = (kPts + 255) / 256;          // 5412
constexpr int kTransBlks = kBN * (kHW / 64);            // 528
constexpr int kStatsBlks = (kCols + 255) / 256;         // 132
constexpr int kPrepBlks = kCountBlks + kTransBlks + kStatsBlks;
constexpr int kAllocBlks = (kBVox + 1023) / 1024;       // 79
}  // namespace

// Blocks fp-contraction (hipcc -ffp-contract=fast would fuse mul+sub into
// fma and change voxel binning vs the per-op f32 numpy reference).
#define FP_BARRIER(x) asm volatile("" : "+v"(x))

// Fused prep kernel, block-range partitioned (all three parts independent):
//   blocks [0, kCountBlks)        : voxel-bin + count per (b,voxel)
//   blocks [kCountBlks, +kTrans)  : feat [bn][c][hw] -> featT [bn][hw][c]
//   blocks [.., +kStatsBlks)      : softmax stats (col max, sum of exp)
__global__ void __launch_bounds__(256) lss_prep(
    const float* __restrict__ feat, float* __restrict__ featT,
    const float* __restrict__ logits, float* __restrict__ cmax,
    float* __restrict__ csum, const float* __restrict__ geom,
    uint16_t* __restrict__ vox16, unsigned* __restrict__ cnt) {
  __shared__ float t[64][65];
  int blk = blockIdx.x;
  if (blk < kCountBlks) {
    // ---- count: per-op f32 voxel binning (proven R7 semantics) ----
    int i = blk * 256 + threadIdx.x;
    if (i >= kPts) return;
    size_t g = (size_t)i * 3;
    float gx = geom[g + 0];
    float gy = geom[g + 1];
    float gz = geom[g + 2];
    float px = __fmul_rn(gx, 100.0f); FP_BARRIER(px);
    float py = __fmul_rn(gy, 100.0f); FP_BARRIER(py);
    float pz = __fmul_rn(gz, 20.0f);  FP_BARRIER(pz);
    float wx = __fsub_rn(px, 50.0f);  FP_BARRIER(wx);
    float wy = __fsub_rn(py, 50.0f);  FP_BARRIER(wy);
    float wz = __fsub_rn(pz, 10.0f);  FP_BARRIER(wz);
    float tx = __fadd_rn(wx, 50.0f);  FP_BARRIER(tx);
    float ty = __fadd_rn(wy, 50.0f);  FP_BARRIER(ty);
    float tz = __fadd_rn(wz, 10.0f);  FP_BARRIER(tz);
    float qx = __fdiv_rn(tx, 0.5f);   FP_BARRIER(qx);
    float qy = __fdiv_rn(ty, 0.5f);   FP_BARRIER(qy);
    float qz = __fdiv_rn(tz, 20.0f);  FP_BARRIER(qz);
    int ix = (int)floorf(qx);
    int iy = (int)floorf(qy);
    int iz = (int)floorf(qz);
    uint16_t v = 0xFFFFu;
    if ((unsigned)ix < (unsigned)kNX && (unsigned)iy < (unsigned)kNX &&
        (unsigned)iz < 1u) {
      int vox = ix * kNX + iy;          // < 40000, fits uint16
      v = (uint16_t)vox;
      int b = i / kPtsPerB;
      atomicAdd(&cnt[b * kVox + vox], 1u);
    }
    vox16[i] = v;
  } else if (blk < kCountBlks + kTransBlks) {
    // ---- transpose (LDS tile) ----
    int tb = blk - kCountBlks;
    int bn = tb / 44;                  // kHW = 44*64
    int hw0 = (tb % 44) * 64;
    const float* src = feat + (size_t)bn * kC * kHW;
#pragma unroll
    for (int p = 0; p < 16; ++p) {     // read coalesced in hw
      int c = p * 4 + (threadIdx.x >> 6);
      int hw = threadIdx.x & 63;
      t[hw][c] = src[(size_t)c * kHW + hw0 + hw];
    }
    __syncthreads();
    float* dst = featT + ((size_t)bn * kHW + hw0) * kC;
#pragma unroll
    for (int p = 0; p < 16; ++p) {     // write coalesced in c
      int hw = p * 4 + (threadIdx.x >> 6);
      int c = threadIdx.x & 63;
      dst[(size_t)hw * kC + c] = t[hw][c];
    }
  } else {
    // ---- softmax stats ----
    int col = (blk - kCountBlks - kTransBlks) * 256 + threadIdx.x;
    if (col >= kCols) return;
    int bn = col / kHW;
    int hw = col - bn * kHW;
    const float* p = logits + (size_t)bn * kD * kHW + hw;
    float m = -INFINITY;
#pragma unroll
    for (int d = 0; d < kD; ++d) m = fmaxf(m, p[(size_t)d * kHW]);
    float s = 0.0f;
#pragma unroll
    for (int d = 0; d < kD; ++d) s += expf(p[(size_t)d * kHW] - m);
    cmax[col] = m;
    csum[col] = s;
  }
}

// Segment allocator (replaces the 127µs single-block scan): per-block
// exclusive scan of counts in LDS + ONE global atomicAdd per block to
// allocate the block's span in `list`. Segment placement is order-free;
// gather only needs [seg[v], cur[v]). 79 blocks, fully parallel.
__global__ void __launch_bounds__(1024) lss_alloc(
    const unsigned* __restrict__ cnt, unsigned* __restrict__ seg,
    unsigned* __restrict__ cur, unsigned* __restrict__ cursor) {
  __shared__ unsigned lds[1024];
  __shared__ unsigned sbase;
  int t = threadIdx.x;
  int v = blockIdx.x * 1024 + t;
  unsigned c = (v < kBVox) ? cnt[v] : 0u;
  lds[t] = c;
  __syncthreads();
  for (int o = 1; o < 1024; o <<= 1) {   // inclusive scan (Hillis-Steele)
    unsigned y = (t >= o) ? lds[t - o] : 0u;
    __syncthreads();
    lds[t] += y;
    __syncthreads();
  }
  if (t == 1023) sbase = atomicAdd(cursor, lds[1023]);
  __syncthreads();
  if (v < kBVox) {
    unsigned start = sbase + lds[t] - c;  // exclusive prefix + block base
    seg[v] = start;
    cur[v] = start;
  }
}

// Fill CSR entries {col, wgt}: pos = atomicAdd(cur[v]).
__global__ void __launch_bounds__(256) lss_fill(
    const float* __restrict__ logits, const uint16_t* __restrict__ vox16,
    const float* __restrict__ cmax, const float* __restrict__ csum,
    unsigned* __restrict__ cur, uint2* __restrict__ list) {
  int i = blockIdx.x * 256 + threadIdx.x;
  if (i >= kPts) return;
  unsigned v = vox16[i];
  if (v == 0xFFFFu) return;
  int hw = i % kHW;
  int bn = i / (kD * kHW);
  int b = i / kPtsPerB;
  int col = bn * kHW + hw;
  float wgt = expf(logits[i] - cmax[col]) / csum[col];
  unsigned pos = atomicAdd(&cur[b * kVox + (int)v], 1u);
  list[pos] = make_uint2((unsigned)col, __float_as_uint(wgt));
}

// Gather: one wave per (b,voxel); lane = channel. 4-way unrolled entry loop
// -> 4 independent outstanding featT loads. One plain store per output
// element; every cell written (no output memset needed).
__global__ void __launch_bounds__(256) lss_gather(
    const unsigned* __restrict__ seg, const unsigned* __restrict__ cur,
    const uint2* __restrict__ list, const float* __restrict__ featT,
    float* __restrict__ out) {
  int wid = threadIdx.x >> 6, lane = threadIdx.x & 63;
  int v = blockIdx.x * 4 + wid;
  if (v >= kBVox) return;
  unsigned s = seg[v];
  unsigned e = cur[v];  // post-fill: segment end
  float acc = 0.0f;
  for (; s + 4 <= e; s += 4) {
    uint2 e0 = list[s + 0];
    uint2 e1 = list[s + 1];
    uint2 e2 = list[s + 2];
    uint2 e3 = list[s + 3];
    float f0 = featT[(size_t)e0.x * kC + lane];
    float f1 = featT[(size_t)e1.x * kC + lane];
    float f2 = featT[(size_t)e2.x * kC + lane];
    float f3 = featT[(size_t)e3.x * kC + lane];
    acc += __uint_as_float(e0.y) * f0;
    acc += __uint_as_float(e1.y) * f1;
    acc += __uint_as_float(e2.y) * f2;
    acc += __uint_as_float(e3.y) * f3;
  }
  for (; s < e; ++s) {
    uint2 ent = list[s];
    acc += __uint_as_float(ent.y) * featT[(size_t)ent.x * kC + lane];
  }
  int b = v / kVox, vox = v - (v / kVox) * kVox;
  out[(size_t)(b * kC + lane) * kVox + vox] = acc;
}

extern "C" void kernel_launch(void* const* d_in, const int* in_sizes, int n_in,
                              void* d_out, int out_size, void* d_ws,
                              size_t ws_size, hipStream_t stream) {
  const float* feat = (const float*)d_in[0];
  const float* logits = (const float*)d_in[1];
  const float* geom = (const float*)d_in[2];
  float* out = (float*)d_out;

  // Workspace layout (8B-aligned first): total ~23.8 MB
  char* w = (char*)d_ws;
  uint2* list = (uint2*)w;        w += (size_t)kPts * 8;            // 11.08MB
  float* featT = (float*)w;       w += (size_t)kBN * kHW * kC * 4;  // 8.65MB
  float* cmax = (float*)w;        w += (size_t)kCols * 4;
  float* csum = (float*)w;        w += (size_t)kCols * 4;
  unsigned* cnt = (unsigned*)w;   w += (size_t)kBVox * 4;
  unsigned* cursor = (unsigned*)w; w += 16;                         // 16B pad
  unsigned* seg = (unsigned*)w;   w += (size_t)kBVox * 4;
  unsigned* cur = (unsigned*)w;   w += (size_t)kBVox * 4;
  uint16_t* vox16 = (uint16_t*)w;                                   // 2.77MB

  // Zero cnt + cursor in one memset (adjacent in layout).
  hipMemsetAsync(cnt, 0, (size_t)kBVox * sizeof(unsigned) + 16, stream);

  lss_prep<<<kPrepBlks, 256, 0, stream>>>(feat, featT, logits, cmax, csum,
                                          geom, vox16, cnt);
  lss_alloc<<<kAllocBlks, 1024, 0, stream>>>(cnt, seg, cur, cursor);
  lss_fill<<<(kPts + 255) / 256, 256, 0, stream>>>(logits, vox16, cmax, csum,
                                                   cur, list);
  lss_gather<<<(kBVox + 3) / 4, 256, 0, stream>>>(seg, cur, list, featT, out);
}